// Round 4
// baseline (527.716 us; speedup 1.0000x reference)
//
#include <hip/hip_runtime.h>
#include <stdint.h>

#define NN 8192
#define DIM 128
#define ALPHA 0.2f
#define MTILE 32
#define BTHREADS 512   // 8 waves
#define KSPLIT 4       // grid = 256 x 4 = 1024 blocks -> 32 waves/CU (full occupancy)

typedef float f32x16 __attribute__((ext_vector_type(16)));
typedef short bf16x8 __attribute__((ext_vector_type(8)));

__device__ __forceinline__ float b2f(uint32_t u){
  uint32_t x = u << 16;
  float f;
  __builtin_memcpy(&f, &x, 4);
  return f;
}
__device__ __forceinline__ uint16_t f2b(float f){
  uint32_t x;
  __builtin_memcpy(&x, &f, 4);
  x += 0x7FFFu + ((x >> 16) & 1u);
  return (uint16_t)(x >> 16);
}

__global__ void zero_kernel(float* __restrict__ p, int n){
  int i = blockIdx.x * 256 + threadIdx.x;
  if (i < n) p[i] = 0.f;
}

// s1[i] = nodes[i,:] . a[0:128], s2[i] = nodes[i,:] . a[128:256]  (all fp32)
__global__ void s_kernel(const float* __restrict__ nodes,
                         const float* __restrict__ a,
                         float* __restrict__ s1, float* __restrict__ s2){
  int row  = blockIdx.x * 4 + (threadIdx.x >> 6);
  int lane = threadIdx.x & 63;
  float2 nv  = *(const float2*)(nodes + row * DIM + lane * 2);
  float2 a1v = *(const float2*)(a + lane * 2);
  float2 a2v = *(const float2*)(a + DIM + lane * 2);
  float p1 = nv.x * a1v.x + nv.y * a1v.y;
  float p2 = nv.x * a2v.x + nv.y * a2v.y;
  #pragma unroll
  for (int off = 32; off; off >>= 1){
    p1 += __shfl_down(p1, off);
    p2 += __shfl_down(p2, off);
  }
  if (lane == 0){ s1[row] = p1; s2[row] = p2; }
}

// nodesT[n][k] = bf16(nodes[k][n])   (fp32 in, bf16 transposed out)
__global__ void t_kernel(const float* __restrict__ nodes,
                         uint16_t* __restrict__ nodesT){
  __shared__ uint16_t tile[32][33];
  int kb = blockIdx.x * 32, nb = blockIdx.y * 32;
  int tx = threadIdx.x & 31, ty = threadIdx.x >> 5;
  for (int r = ty; r < 32; r += 8)
    tile[r][tx] = f2b(nodes[(size_t)(kb + r) * DIM + nb + tx]);
  __syncthreads();
  for (int r = ty; r < 32; r += 8)
    nodesT[(size_t)(nb + r) * NN + kb + tx] = tile[tx][r];
}

// Fused: W = mask * exp(leaky(s1+s2)); partial (W @ nodes) and rowsum(W)
// accumulated into global fp32 buffers via atomics. KSPLIT blocks per M-tile.
__global__ void __launch_bounds__(BTHREADS)
attn_kernel(const float* __restrict__ dist,
            const uint16_t* __restrict__ nodesT,
            const float* __restrict__ s1,
            const float* __restrict__ s2,
            float* __restrict__ acc_g,    // [NN][DIM]
            float* __restrict__ den_g){   // [NN]
  const int tid  = threadIdx.x;
  const int wave = tid >> 6;    // 0..7
  const int lane = tid & 63;
  const int m    = lane & 31;   // A row / B-D column index
  const int half = lane >> 5;   // k-half within MFMA
  const int i0   = blockIdx.x * MTILE;
  const int kb   = blockIdx.y;

  const float s1v = s1[i0 + m];

  const int kblk  = NN / KSPLIT;                     // 2048 per block
  const int kwave = kblk / (BTHREADS / 64);          // 256 per wave
  const int kbeg  = kb * kblk + wave * kwave;
  const int steps = kwave / 16;                      // 16

  f32x16 acc0, acc1, acc2, acc3;
  #pragma unroll
  for (int i = 0; i < 16; i++){ acc0[i] = 0.f; acc1[i] = 0.f; acc2[i] = 0.f; acc3[i] = 0.f; }
  float den = 0.f;

  const float*    dp  = dist   + (size_t)(i0 + m) * NN + kbeg + half * 8;
  const float*    sp  = s2     + kbeg + half * 8;
  const uint16_t* b0p = nodesT + (size_t)m * NN + kbeg + half * 8;
  const uint16_t* b1p = b0p + (size_t)32 * NN;
  const uint16_t* b2p = b0p + (size_t)64 * NN;
  const uint16_t* b3p = b0p + (size_t)96 * NN;

  for (int s = 0; s < steps; s++){
    float4 da  = *(const float4*)dp;
    float4 db  = *(const float4*)(dp + 4);
    float4 sa  = *(const float4*)sp;
    float4 sb  = *(const float4*)(sp + 4);
    uint4  nb0 = *(const uint4*)b0p;
    uint4  nb1 = *(const uint4*)b1p;
    uint4  nb2 = *(const uint4*)b2p;
    uint4  nb3 = *(const uint4*)b3p;

    float dv[8]  = {da.x, da.y, da.z, da.w, db.x, db.y, db.z, db.w};
    float s2v[8] = {sa.x, sa.y, sa.z, sa.w, sb.x, sb.y, sb.z, sb.w};

    union { bf16x8 v; uint16_t u[8]; } af;
    #pragma unroll
    for (int j = 0; j < 8; j++){
      float x = s1v + s2v[j];
      float e = fmaxf(x, ALPHA * x);
      float w = (dv[j] < 0.5f) ? __expf(e) : 0.f;
      uint16_t wq = f2b(w);
      af.u[j] = wq;
      den += b2f((uint32_t)wq);   // denominator from quantized weights
    }

    acc0 = __builtin_amdgcn_mfma_f32_32x32x16_bf16(af.v, *(const bf16x8*)&nb0, acc0, 0, 0, 0);
    acc1 = __builtin_amdgcn_mfma_f32_32x32x16_bf16(af.v, *(const bf16x8*)&nb1, acc1, 0, 0, 0);
    acc2 = __builtin_amdgcn_mfma_f32_32x32x16_bf16(af.v, *(const bf16x8*)&nb2, acc2, 0, 0, 0);
    acc3 = __builtin_amdgcn_mfma_f32_32x32x16_bf16(af.v, *(const bf16x8*)&nb3, acc3, 0, 0, 0);

    dp  += 16; sp  += 16;
    b0p += 16; b1p += 16; b2p += 16; b3p += 16;
  }

  // Combine 8 waves' partial tiles + denominators in LDS.
  __shared__ float accT[MTILE][DIM];
  __shared__ float denT[MTILE];
  for (int idx = tid; idx < MTILE * DIM; idx += BTHREADS) ((float*)accT)[idx] = 0.f;
  if (tid < MTILE) denT[tid] = 0.f;
  __syncthreads();

  #pragma unroll
  for (int r = 0; r < 16; r++){
    int row = (r & 3) + 8 * (r >> 2) + 4 * half;  // verified 32x32 C/D layout
    atomicAdd(&accT[row][ 0 + m], acc0[r]);
    atomicAdd(&accT[row][32 + m], acc1[r]);
    atomicAdd(&accT[row][64 + m], acc2[r]);
    atomicAdd(&accT[row][96 + m], acc3[r]);
  }
  atomicAdd(&denT[m], den);
  __syncthreads();

  // Spill block partials to global accumulators (device-scope atomics).
  float* ag = acc_g + (size_t)i0 * DIM;
  for (int idx = tid; idx < MTILE * DIM; idx += BTHREADS)
    atomicAdd(&ag[idx], ((float*)accT)[idx]);
  if (tid < MTILE) atomicAdd(&den_g[i0 + tid], denT[tid]);
}

// out = acc / den   (fp32)
__global__ void norm_kernel(const float* __restrict__ acc_g,
                            const float* __restrict__ den_g,
                            float* __restrict__ out){
  int gid = blockIdx.x * 256 + threadIdx.x;
  int row = gid >> 7;
  out[gid] = acc_g[gid] / den_g[row];
}

extern "C" void kernel_launch(void* const* d_in, const int* in_sizes, int n_in,
                              void* d_out, int out_size, void* d_ws, size_t ws_size,
                              hipStream_t stream){
  const float* nodes = (const float*)d_in[0];
  const float* dist  = (const float*)d_in[1];
  const float* a     = (const float*)d_in[2];
  float* out = (float*)d_out;

  char* ws = (char*)d_ws;
  float*    s1     = (float*)ws;                                  // 32 KB
  float*    s2     = (float*)(ws + (32 << 10));                   // 32 KB
  uint16_t* nodesT = (uint16_t*)(ws + (64 << 10));                // 2 MB
  float*    acc_g  = (float*)(ws + (64 << 10) + (2 << 20));       // 4 MB
  float*    den_g  = (float*)(ws + (64 << 10) + (6 << 20));       // 32 KB
  // total ~6.2 MB

  const int nz = NN * DIM + NN;   // acc_g is contiguous with den_g? (not quite; zero separately)
  (void)nz;
  zero_kernel<<<(NN * DIM + 255) / 256, 256, 0, stream>>>(acc_g, NN * DIM);
  zero_kernel<<<(NN + 255) / 256, 256, 0, stream>>>(den_g, NN);
  s_kernel<<<NN / 4, 256, 0, stream>>>(nodes, a, s1, s2);
  t_kernel<<<dim3(NN / 32, DIM / 32), 256, 0, stream>>>(nodes, nodesT);
  attn_kernel<<<dim3(NN / MTILE, KSPLIT), BTHREADS, 0, stream>>>(dist, nodesT, s1, s2, acc_g, den_g);
  norm_kernel<<<NN * DIM / 256, 256, 0, stream>>>(acc_g, den_g, out);
}

// Round 5
// 394.698 us; speedup vs baseline: 1.3370x; 1.3370x over previous
//
#include <hip/hip_runtime.h>
#include <stdint.h>

#define NN 8192
#define DIM 128
#define ALPHA 0.2f
#define MTILE 32
#define BTHREADS 512          // 8 waves = 4 n-quarters x 2 k-halves
#define BK 256                // k-chunk per LDS tile
#define NCHUNK (NN / BK)      // 32
#define WSTRIDE (BK + 8)      // +16B pad to spread LDS banks

typedef float f32x16 __attribute__((ext_vector_type(16)));
typedef short bf16x8 __attribute__((ext_vector_type(8)));

__device__ __forceinline__ float b2f(uint32_t u){
  uint32_t x = u << 16;
  float f;
  __builtin_memcpy(&f, &x, 4);
  return f;
}
__device__ __forceinline__ uint16_t f2b(float f){
  uint32_t x;
  __builtin_memcpy(&x, &f, 4);
  x += 0x7FFFu + ((x >> 16) & 1u);
  return (uint16_t)(x >> 16);
}

// s1[i] = nodes[i,:] . a[0:128], s2[i] = nodes[i,:] . a[128:256]  (all fp32)
__global__ void s_kernel(const float* __restrict__ nodes,
                         const float* __restrict__ a,
                         float* __restrict__ s1, float* __restrict__ s2){
  int row  = blockIdx.x * 4 + (threadIdx.x >> 6);
  int lane = threadIdx.x & 63;
  float2 nv  = *(const float2*)(nodes + row * DIM + lane * 2);
  float2 a1v = *(const float2*)(a + lane * 2);
  float2 a2v = *(const float2*)(a + DIM + lane * 2);
  float p1 = nv.x * a1v.x + nv.y * a1v.y;
  float p2 = nv.x * a2v.x + nv.y * a2v.y;
  #pragma unroll
  for (int off = 32; off; off >>= 1){
    p1 += __shfl_down(p1, off);
    p2 += __shfl_down(p2, off);
  }
  if (lane == 0){ s1[row] = p1; s2[row] = p2; }
}

// nodesT[n][k] = bf16(nodes[k][n])
__global__ void t_kernel(const float* __restrict__ nodes,
                         uint16_t* __restrict__ nodesT){
  __shared__ uint16_t tile[32][33];
  int kb = blockIdx.x * 32, nb = blockIdx.y * 32;
  int tx = threadIdx.x & 31, ty = threadIdx.x >> 5;
  for (int r = ty; r < 32; r += 8)
    tile[r][tx] = f2b(nodes[(size_t)(kb + r) * DIM + nb + tx]);
  __syncthreads();
  for (int r = ty; r < 32; r += 8)
    nodesT[(size_t)(nb + r) * NN + kb + tx] = tile[tx][r];
}

// Fused GAT row-block: coalesced dist stream -> W tile in LDS -> MFMA.
__global__ void __launch_bounds__(BTHREADS)
attn_kernel(const float* __restrict__ dist,
            const uint16_t* __restrict__ nodesT,
            const float* __restrict__ s1,
            const float* __restrict__ s2,
            float* __restrict__ out){
  __shared__ uint16_t Wbuf[2][MTILE][WSTRIDE];   // 33.8 KB
  __shared__ float accT[MTILE][DIM];             // 16 KB
  __shared__ float denT[MTILE];

  const int tid  = threadIdx.x;
  const int lane = tid & 63;
  const int wave = tid >> 6;
  const int i0   = blockIdx.x * MTILE;

  // ---- W-gen mapping: thread -> (row, 16 k's split as r*8 + {0,128}) ----
  const int wrow = tid >> 4;          // 0..31
  const int wr   = tid & 15;          // 0..15
  const float s1v = s1[i0 + wrow];
  const float* distRow = dist + (size_t)(i0 + wrow) * NN + wr * 8;

  // ---- MFMA mapping: wave -> (n-quarter q, k-half h) ----
  const int q    = wave & 3;
  const int h    = wave >> 2;
  const int m    = lane & 31;
  const int half = lane >> 5;
  const uint16_t* bRow = nodesT + (size_t)(q * 32 + m) * NN;

  f32x16 acc;
  #pragma unroll
  for (int i = 0; i < 16; i++) acc[i] = 0.f;
  float den = 0.f;

  float4 pd0, pd1, pd2, pd3, ps0, ps1, ps2, ps3;

  auto load_chunk = [&](int s){
    const float* dpp = distRow + s * BK;
    const float* spp = s2 + s * BK + wr * 8;
    pd0 = *(const float4*)(dpp);
    pd1 = *(const float4*)(dpp + 4);
    pd2 = *(const float4*)(dpp + 128);
    pd3 = *(const float4*)(dpp + 132);
    ps0 = *(const float4*)(spp);
    ps1 = *(const float4*)(spp + 4);
    ps2 = *(const float4*)(spp + 128);
    ps3 = *(const float4*)(spp + 132);
  };

  auto gen_write = [&](int buf){
    float dv[16] = {pd0.x, pd0.y, pd0.z, pd0.w, pd1.x, pd1.y, pd1.z, pd1.w,
                    pd2.x, pd2.y, pd2.z, pd2.w, pd3.x, pd3.y, pd3.z, pd3.w};
    float sv[16] = {ps0.x, ps0.y, ps0.z, ps0.w, ps1.x, ps1.y, ps1.z, ps1.w,
                    ps2.x, ps2.y, ps2.z, ps2.w, ps3.x, ps3.y, ps3.z, ps3.w};
    union { bf16x8 v; uint16_t u[8]; } w0, w1;
    #pragma unroll
    for (int j = 0; j < 8; j++){
      float x = s1v + sv[j];
      float e = fmaxf(x, ALPHA * x);
      float w = (dv[j] < 0.5f) ? __expf(e) : 0.f;
      uint16_t wq = f2b(w);
      w0.u[j] = wq;
      den += b2f((uint32_t)wq);
    }
    #pragma unroll
    for (int j = 0; j < 8; j++){
      float x = s1v + sv[8 + j];
      float e = fmaxf(x, ALPHA * x);
      float w = (dv[8 + j] < 0.5f) ? __expf(e) : 0.f;
      uint16_t wq = f2b(w);
      w1.u[j] = wq;
      den += b2f((uint32_t)wq);
    }
    *(bf16x8*)&Wbuf[buf][wrow][wr * 8]       = w0.v;
    *(bf16x8*)&Wbuf[buf][wrow][wr * 8 + 128] = w1.v;
  };

  // Prologue: chunk 0 into buf 0.
  load_chunk(0);
  gen_write(0);

  for (int s = 0; s < NCHUNK; s++){
    if (s + 1 < NCHUNK) load_chunk(s + 1);   // HBM prefetch, overlaps MFMA
    __syncthreads();
    const int buf = s & 1;
    const size_t kb = (size_t)s * BK;
    #pragma unroll
    for (int kk = 0; kk < 8; kk++){
      int ko = h * 128 + kk * 16 + half * 8;
      bf16x8 av = *(const bf16x8*)&Wbuf[buf][m][ko];
      bf16x8 bv = *(const bf16x8*)(bRow + kb + ko);
      acc = __builtin_amdgcn_mfma_f32_32x32x16_bf16(av, bv, acc, 0, 0, 0);
    }
    if (s + 1 < NCHUNK) gen_write((s + 1) & 1);
  }

  // ---- denominator: 16 threads per row, all in one wave -> shfl reduce ----
  den += __shfl_down(den, 8, 16);
  den += __shfl_down(den, 4, 16);
  den += __shfl_down(den, 2, 16);
  den += __shfl_down(den, 1, 16);
  if (wr == 0) denT[wrow] = 1.0f / den;

  // ---- combine k-half pairs via LDS, normalize, store fp32 ----
  if (h == 0){
    #pragma unroll
    for (int r = 0; r < 16; r++){
      int row = (r & 3) + 8 * (r >> 2) + 4 * half;
      accT[row][q * 32 + m] = acc[r];
    }
  }
  __syncthreads();
  if (h == 1){
    #pragma unroll
    for (int r = 0; r < 16; r++){
      int row = (r & 3) + 8 * (r >> 2) + 4 * half;
      float v = (accT[row][q * 32 + m] + acc[r]) * denT[row];
      out[(size_t)(i0 + row) * DIM + q * 32 + m] = v;
    }
  }
}

extern "C" void kernel_launch(void* const* d_in, const int* in_sizes, int n_in,
                              void* d_out, int out_size, void* d_ws, size_t ws_size,
                              hipStream_t stream){
  const float* nodes = (const float*)d_in[0];
  const float* dist  = (const float*)d_in[1];
  const float* a     = (const float*)d_in[2];
  float* out = (float*)d_out;

  char* ws = (char*)d_ws;
  float*    s1     = (float*)ws;                     // 32 KB
  float*    s2     = (float*)(ws + (32 << 10));      // 32 KB
  uint16_t* nodesT = (uint16_t*)(ws + (64 << 10));   // 2 MB

  s_kernel<<<NN / 4, 256, 0, stream>>>(nodes, a, s1, s2);
  t_kernel<<<dim3(NN / 32, DIM / 32), 256, 0, stream>>>(nodes, nodesT);
  attn_kernel<<<NN / MTILE, BTHREADS, 0, stream>>>(dist, nodesT, s1, s2, out);
}